// Round 5
// baseline (190.551 us; speedup 1.0000x reference)
//
#include <hip/hip_runtime.h>

// Problem: MultiHeadGraphAttentionLayer_28956669509709  (fp32 I/O per reference)
// Identity: sum_j softmax(e)[...,j] == 1  =>  attention is a no-op, out = hp.
// out[b,n,h*64+d] = a*hp[h,b,n,d] + (1-a)*h[b,n,h*64+d],  a = clip(res_alpha,0,1)
// Fold residual into the weight:  out = h @ (a*Wc + (1-a)*I256)   (Wc block-diag)
// => ONE pure GEMM [16384x256] @ [256x256] (bf16 MFMA, fp32 acc). adj untouched.
//
// Measured context (R2-R4): the ~183us window = 2x ~78us unconditional 512MiB
// workspace-poison fills (harness; proved unconditional in R3) + ~26us ours.
//
// R5: delete LDS entirely from the GEMM. Per wave, the A-fragment (16 rows x
// 32 k) is loaded straight from global h in MFMA fragment order (2 dwordx4
// per kt; the 4 waves of a block are 4 heads sharing the SAME 16 h-rows, and
// a 16x1KB tile fits 32KB L1 -> 3 of 4 waves L1-hit). fp32->bf16 via compiler
// __bf16 casts (emits v_cvt_pk_bf16_f32: 4 ops/fragment vs manual RNE ~32).
// No LDS write, no barrier, no LDS read: pure load->cvt->MFMA->store stream,
// software-pipelined over kt. B stays pre-packed (1KiB coalesced wave loads).

typedef unsigned short ushort_t;
typedef __bf16 bf16x8 __attribute__((ext_vector_type(8)));
typedef float floatx4 __attribute__((ext_vector_type(4)));

__device__ __forceinline__ ushort_t f2bf(float f) {
    unsigned int x;
    __builtin_memcpy(&x, &f, 4);
    // round to nearest even
    return (ushort_t)((x + 0x7fffu + ((x >> 16) & 1u)) >> 16);
}

// ---------------------------------------------------------------------------
// Kernel 1: W fp32 [H=4][F=256][D=64] -> Wb bf16 in MFMA fragment order,
// with the residual folded in:
//   val(k,n) = a*Wc[k][n] + (1-a)*(k==n),  k=f global, n=h*64+d
//   Wb[h][kt][nt][lane][j] = bf16( val( kt*32+(lane>>4)*8+j, h*64+nt*16+(lane&15) ) )
// grid: 16 blocks (h = bid>>2, f-chunk = bid&3), 256 threads
// ---------------------------------------------------------------------------
__global__ __launch_bounds__(256) void pack_w(const float* __restrict__ W,
                                              const float* __restrict__ alpha_p,
                                              ushort_t* __restrict__ Wb) {
    __shared__ float tile[64][68];  // [f_local][d], +4 pad breaks bank stride
    const int h  = blockIdx.x >> 2;
    const int f0 = (blockIdx.x & 3) * 64;
    const int t  = threadIdx.x;

    float av = *alpha_p;
    av = fminf(fmaxf(av, 0.0f), 1.0f);
    const float bv = 1.0f - av;

    // coalesced fp32 load (d contiguous per f-row) into LDS (keep fp32)
    #pragma unroll
    for (int p = 0; p < 2; ++p) {
        const int fl = p * 32 + (t >> 3);
        const int d0 = (t & 7) * 8;
        const float* src = W + h * 16384 + (f0 + fl) * 64 + d0;
        *(float4*)&tile[fl][d0]     = *(const float4*)(src);
        *(float4*)&tile[fl][d0 + 4] = *(const float4*)(src + 4);
    }
    __syncthreads();

    // write packed fragments: this f-chunk covers kt = f0/32 .. f0/32+1
    #pragma unroll
    for (int p = 0; p < 2; ++p) {
        const int c    = p * 256 + t;    // 512 fragment-chunks of 8 elements
        const int kt2  = c >> 8;         // 0..1 (local kt within this f-chunk)
        const int nt   = (c >> 6) & 3;
        const int lane = c & 63;
        const int kt   = (f0 >> 5) + kt2;
        const int d    = nt * 16 + (lane & 15);   // 0..63, col n = h*64+d
        const int nglb = h * 64 + d;
        ushort_t tmp[8];
        #pragma unroll
        for (int j = 0; j < 8; ++j) {
            const int kglb = f0 + kt2 * 32 + ((lane >> 4) * 8) + j;
            float v = av * tile[kt2 * 32 + (lane >> 4) * 8 + j][d];
            if (kglb == nglb) v += bv;   // folded (1-a)*I
            tmp[j] = f2bf(v);
        }
        *(uint4*)(Wb + (size_t)(((h * 8 + kt) * 4 + nt) * 64 + lane) * 8) =
            *(const uint4*)tmp;
    }
}

// ---------------------------------------------------------------------------
// Kernel 2: out = h @ W'  — LDS-free, barrier-free.
//   grid: 1024 blocks x 256 threads; block = 16 rows, wave w = head w.
//   Wave: 16 rows x 64 cols = acc[4] of 16x16x32, K pipelined over 8 steps.
// ---------------------------------------------------------------------------
__global__ __launch_bounds__(256) void gat_gemm(const float* __restrict__ hIn,
                                                const ushort_t* __restrict__ Wb,
                                                float* __restrict__ out) {
    const int t  = threadIdx.x;
    const int m0 = blockIdx.x * 16;

    const int w    = t >> 6;   // head index, cols [w*64, w*64+64)
    const int lane = t & 63;
    const int quad = lane >> 4;
    const int l16  = lane & 15;

    // A source: row (m0+l16), k walks kt*32 + quad*8 (+0..7)
    const float* asrc = hIn + (size_t)(m0 + l16) * 256 + quad * 8;
    // B-fragment base for this head+lane; + kt*2048 + nt*512 walks fragments
    const ushort_t* wbase = Wb + (size_t)w * 16384 + lane * 8;

    // prefetch kt=0
    float4 a0 = *(const float4*)(asrc);
    float4 a1 = *(const float4*)(asrc + 4);
    bf16x8 b[4];
    #pragma unroll
    for (int nt = 0; nt < 4; ++nt)
        b[nt] = *(const bf16x8*)(wbase + nt * 512);

    floatx4 acc[4] = {};

    #pragma unroll
    for (int kt = 0; kt < 8; ++kt) {
        // issue kt+1 loads over kt's convert + MFMAs
        float4 a0n, a1n;
        bf16x8 bn[4];
        if (kt < 7) {
            const float* an = asrc + (kt + 1) * 32;
            a0n = *(const float4*)(an);
            a1n = *(const float4*)(an + 4);
            #pragma unroll
            for (int nt = 0; nt < 4; ++nt)
                bn[nt] = *(const bf16x8*)(wbase + (kt + 1) * 2048 + nt * 512);
        }

        // fp32 -> bf16 fragment (compiler emits v_cvt_pk_bf16_f32 pairs)
        bf16x8 af = { (__bf16)a0.x, (__bf16)a0.y, (__bf16)a0.z, (__bf16)a0.w,
                      (__bf16)a1.x, (__bf16)a1.y, (__bf16)a1.z, (__bf16)a1.w };

        #pragma unroll
        for (int nt = 0; nt < 4; ++nt)
            acc[nt] = __builtin_amdgcn_mfma_f32_16x16x32_bf16(
                af, b[nt], acc[nt], 0, 0, 0);

        if (kt < 7) {
            a0 = a0n; a1 = a1n;
            #pragma unroll
            for (int nt = 0; nt < 4; ++nt) b[nt] = bn[nt];
        }
    }

    // epilogue: pure stores (residual already folded into W')
    // C/D layout (m89-verified): col = lane&15, row = quad*4 + reg
    #pragma unroll
    for (int r = 0; r < 4; ++r) {
        const int row = m0 + quad * 4 + r;
        #pragma unroll
        for (int nt = 0; nt < 4; ++nt) {
            const int col = w * 64 + nt * 16 + l16;
            out[(size_t)row * 256 + col] = acc[nt][r];
        }
    }
}

extern "C" void kernel_launch(void* const* d_in, const int* in_sizes, int n_in,
                              void* d_out, int out_size, void* d_ws, size_t ws_size,
                              hipStream_t stream) {
    // inputs (setup_inputs order, all fp32 per reference):
    //   d_in[0] h [8,2048,256], d_in[1] adj [8,2048,2048] (UNUSED),
    //   d_in[2] W [4,256,64],   d_in[3] res_alpha scalar
    const float* h_ptr = (const float*)d_in[0];
    const float* W_ptr = (const float*)d_in[2];
    const float* a_ptr = (const float*)d_in[3];
    float* out_ptr     = (float*)d_out;
    ushort_t* Wb       = (ushort_t*)d_ws;  // 4*8*4*64*8*2 = 128 KB scratch

    pack_w<<<16, 256, 0, stream>>>(W_ptr, a_ptr, Wb);
    gat_gemm<<<1024, 256, 0, stream>>>(h_ptr, Wb, out_ptr);
}

// Round 6
// 182.781 us; speedup vs baseline: 1.0425x; 1.0425x over previous
//
#include <hip/hip_runtime.h>

// Problem: MultiHeadGraphAttentionLayer_28956669509709  (fp32 I/O per reference)
// Identity: sum_j softmax(e)[...,j] == 1  =>  attention is a no-op, out = hp.
// out[b,n,h*64+d] = a*hp[h,b,n,d] + (1-a)*h[b,n,h*64+d],  a = clip(res_alpha,0,1)
// Fold residual into the weight:  out = h @ (a*Wc + (1-a)*I256)   (Wc block-diag)
// => ONE pure GEMM [16384x256] @ [256x256] (bf16 MFMA, fp32 acc). adj untouched.
//
// Measured context: ~182us window = 2x ~78us unconditional 512MiB workspace
// poison fills (harness, proved unconditional in R3) + ~26us controllable.
// R2 (LDS-staged, packed W, folded residual) = 182.4us is the best measured.
// R5 (LDS-free gathered A loads) = 190.6us -> falsified; LDS staging is right.
//
// R6 = R2 structure with the staging path rebuilt on global_load_lds width=16:
//  - h tile staged fp32 directly HBM->LDS (no VGPR round-trip, ZERO staging
//    VALU; was 4 float4 loads + ~128 VALU RNE ops + 4 ds_writes per thread)
//  - LDS kept fp32; fp32->bf16 at fragment read via compiler casts
//    (v_cvt_pk_bf16_f32, 4 ops/fragment; m240: compiler cast is the fast path)
//  - bank conflicts: global_load_lds needs a LINEAR dest, so swizzle is done
//    m173-style: per-lane global source address XORed (lane ^ (row&7)) on 16B
//    slots, read side applies the same XOR -> b128 reads at the 8-lane/group
//    throughput floor (unswizzled would be 2x worse: 16 lanes on 4 groups)

typedef unsigned short ushort_t;
typedef __bf16 bf16x8 __attribute__((ext_vector_type(8)));
typedef float floatx4 __attribute__((ext_vector_type(4)));

__device__ __forceinline__ ushort_t f2bf(float f) {
    unsigned int x;
    __builtin_memcpy(&x, &f, 4);
    // round to nearest even
    return (ushort_t)((x + 0x7fffu + ((x >> 16) & 1u)) >> 16);
}

// async HBM->LDS copy, 16B per lane: dest = ldsbase + lane*16 (wave-uniform
// base), source is per-lane. C-style casts perform the addrspace casts.
__device__ __forceinline__ void gload_lds16(const float* g, void* ldsbase) {
    __builtin_amdgcn_global_load_lds(
        (const __attribute__((address_space(1))) unsigned int*)g,
        (__attribute__((address_space(3))) unsigned int*)ldsbase, 16, 0, 0);
}

// ---------------------------------------------------------------------------
// Kernel 1: W fp32 [H=4][F=256][D=64] -> Wb bf16 in MFMA fragment order,
// with the residual folded in:
//   val(k,n) = a*Wc[k][n] + (1-a)*(k==n),  k=f global, n=h*64+d
//   Wb[h][kt][nt][lane][j] = bf16( val( kt*32+(lane>>4)*8+j, h*64+nt*16+(lane&15) ) )
// Each B-fragment load in the GEMM is then a single coalesced 1KiB wave read.
// grid: 16 blocks (h = bid>>2, f-chunk = bid&3), 256 threads
// ---------------------------------------------------------------------------
__global__ __launch_bounds__(256) void pack_w(const float* __restrict__ W,
                                              const float* __restrict__ alpha_p,
                                              ushort_t* __restrict__ Wb) {
    __shared__ float tile[64][68];  // [f_local][d], +4 pad breaks bank stride
    const int h  = blockIdx.x >> 2;
    const int f0 = (blockIdx.x & 3) * 64;
    const int t  = threadIdx.x;

    float av = *alpha_p;
    av = fminf(fmaxf(av, 0.0f), 1.0f);
    const float bv = 1.0f - av;

    // coalesced fp32 load (d contiguous per f-row) into LDS (keep fp32)
    #pragma unroll
    for (int p = 0; p < 2; ++p) {
        const int fl = p * 32 + (t >> 3);
        const int d0 = (t & 7) * 8;
        const float* src = W + h * 16384 + (f0 + fl) * 64 + d0;
        *(float4*)&tile[fl][d0]     = *(const float4*)(src);
        *(float4*)&tile[fl][d0 + 4] = *(const float4*)(src + 4);
    }
    __syncthreads();

    // write packed fragments: this f-chunk covers kt = f0/32 .. f0/32+1
    #pragma unroll
    for (int p = 0; p < 2; ++p) {
        const int c    = p * 256 + t;    // 512 fragment-chunks of 8 elements
        const int kt2  = c >> 8;         // 0..1 (local kt within this f-chunk)
        const int nt   = (c >> 6) & 3;
        const int lane = c & 63;
        const int kt   = (f0 >> 5) + kt2;
        const int d    = nt * 16 + (lane & 15);   // 0..63, col n = h*64+d
        const int nglb = h * 64 + d;
        ushort_t tmp[8];
        #pragma unroll
        for (int j = 0; j < 8; ++j) {
            const int kglb = f0 + kt2 * 32 + ((lane >> 4) * 8) + j;
            float v = av * tile[kt2 * 32 + (lane >> 4) * 8 + j][d];
            if (kglb == nglb) v += bv;   // folded (1-a)*I
            tmp[j] = f2bf(v);
        }
        *(uint4*)(Wb + (size_t)(((h * 8 + kt) * 4 + nt) * 64 + lane) * 8) =
            *(const uint4*)tmp;
    }
}

// ---------------------------------------------------------------------------
// Kernel 2: out = h @ W'   (fp32 in/out, bf16 MFMA inside, residual pre-folded)
//   grid: 512 blocks x 256 threads; block tile = 32 rows x 256 cols
//   wave w = head w: 32 rows x cols [w*64, w*64+64) -> acc[2][4] of 16x16x32
//   h tile staged fp32 via global_load_lds (32KB LDS), slot-XOR swizzled
// ---------------------------------------------------------------------------
__global__ __launch_bounds__(256) void gat_gemm(const float* __restrict__ hIn,
                                                const ushort_t* __restrict__ Wb,
                                                float* __restrict__ out) {
    // hT4[row][p]: 32 rows x 64 16B-slots; physical slot p holds k-slot
    // s = p ^ (row&7)  (content C[row][s] at p = s ^ (row&7))
    __shared__ float4 hT4[32 * 64];
    const int t  = threadIdx.x;
    const int m0 = blockIdx.x * 32;

    const int w    = t >> 6;   // head index, cols [w*64, w*64+64)
    const int lane = t & 63;
    const int quad = lane >> 4;
    const int l16  = lane & 15;

    // B-fragment base for this head+lane; + kt*2048 + nt*512 walks fragments
    const ushort_t* wbase = Wb + (size_t)w * 16384 + lane * 8;

    // prefetch kt=0 B fragments first (their latency hides under staging)
    bf16x8 b[4];
    #pragma unroll
    for (int nt = 0; nt < 4; ++nt)
        b[nt] = *(const bf16x8*)(wbase + nt * 512);

    // stage 32x256 fp32 h-tile -> LDS, async, 1KB row per wave-instruction.
    // Source pre-swizzled: lane L writes physical slot L, which must hold
    // k-slot L^(r&7) -> per-lane source offset (L ^ (r&7))*4 floats.
    #pragma unroll
    for (int i = 0; i < 8; ++i) {
        const int r = w * 8 + i;
        const float* g = hIn + (size_t)(m0 + r) * 256 + ((lane ^ (r & 7)) << 2);
        gload_lds16(g, &hT4[r * 64]);
    }
    __syncthreads();  // drains vmcnt(0): staging AND B prefetch complete

    floatx4 acc[2][4] = {};

    #pragma unroll
    for (int kt = 0; kt < 8; ++kt) {
        // software-pipeline: issue kt+1 B loads over kt's LDS reads + MFMAs
        bf16x8 bn[4];
        if (kt < 7) {
            #pragma unroll
            for (int nt = 0; nt < 4; ++nt)
                bn[nt] = *(const bf16x8*)(wbase + (kt + 1) * 2048 + nt * 512);
        }

        // A fragments: row = mt*16 + l16, k-slots s0 = kt*8 + quad*2, s0+1
        const int rx = l16 & 7;               // row&7 (same for both mt)
        const int s0 = kt * 8 + quad * 2;
        bf16x8 a[2];
        #pragma unroll
        for (int mt = 0; mt < 2; ++mt) {
            const int row = mt * 16 + l16;
            float4 a0 = hT4[row * 64 + (s0 ^ rx)];
            float4 a1 = hT4[row * 64 + ((s0 + 1) ^ rx)];
            a[mt] = bf16x8{ (__bf16)a0.x, (__bf16)a0.y, (__bf16)a0.z, (__bf16)a0.w,
                            (__bf16)a1.x, (__bf16)a1.y, (__bf16)a1.z, (__bf16)a1.w };
        }

        #pragma unroll
        for (int mt = 0; mt < 2; ++mt)
            #pragma unroll
            for (int nt = 0; nt < 4; ++nt)
                acc[mt][nt] = __builtin_amdgcn_mfma_f32_16x16x32_bf16(
                    a[mt], b[nt], acc[mt][nt], 0, 0, 0);

        if (kt < 7) {
            #pragma unroll
            for (int nt = 0; nt < 4; ++nt) b[nt] = bn[nt];
        }
    }

    // epilogue: pure stores (residual already folded into W')
    // C/D layout (m89-verified): col = lane&15, row = quad*4 + reg
    #pragma unroll
    for (int mt = 0; mt < 2; ++mt) {
        #pragma unroll
        for (int r = 0; r < 4; ++r) {
            const int rl = mt * 16 + quad * 4 + r;
            #pragma unroll
            for (int nt = 0; nt < 4; ++nt) {
                const int col = w * 64 + nt * 16 + l16;
                out[(size_t)(m0 + rl) * 256 + col] = acc[mt][nt][r];
            }
        }
    }
}

extern "C" void kernel_launch(void* const* d_in, const int* in_sizes, int n_in,
                              void* d_out, int out_size, void* d_ws, size_t ws_size,
                              hipStream_t stream) {
    // inputs (setup_inputs order, all fp32 per reference):
    //   d_in[0] h [8,2048,256], d_in[1] adj [8,2048,2048] (UNUSED),
    //   d_in[2] W [4,256,64],   d_in[3] res_alpha scalar
    const float* h_ptr = (const float*)d_in[0];
    const float* W_ptr = (const float*)d_in[2];
    const float* a_ptr = (const float*)d_in[3];
    float* out_ptr     = (float*)d_out;
    ushort_t* Wb       = (ushort_t*)d_ws;  // 4*8*4*64*8*2 = 128 KB scratch

    pack_w<<<16, 256, 0, stream>>>(W_ptr, a_ptr, Wb);
    gat_gemm<<<512, 256, 0, stream>>>(h_ptr, Wb, out_ptr);
}